// Round 5
// baseline (263.664 us; speedup 1.0000x reference)
//
#include <hip/hip_runtime.h>

// ---------- common types / helpers ----------
typedef __attribute__((ext_vector_type(8))) short bf16x8;   // 8 bf16 = 4 VGPRs
typedef __attribute__((ext_vector_type(4))) float f32x4;
typedef __attribute__((ext_vector_type(4))) unsigned int u32x4;
typedef __attribute__((ext_vector_type(2))) unsigned int u32x2;

// q pre-scale: softmax scale (1/sqrt(64)) * log2(e), so P = exp2(S) directly.
#define QSCALE 0.1803368801111243f

__device__ inline unsigned short f2bf(float f) {
  union { float f; unsigned u; } v; v.f = f;
  unsigned r = v.u + 0x7fffu + ((v.u >> 16) & 1u);   // RNE
  return (unsigned short)(r >> 16);
}

// pack two fp32 -> two bf16 (RNE) in one dword: low16 = bf(a), high16 = bf(b)
__device__ inline unsigned packbf2(float a, float b) {
  union { float f; unsigned u; } va, vb; va.f = a; vb.f = b;
  unsigned ta = va.u + 0x7fffu + ((va.u >> 16) & 1u);
  unsigned tb = vb.u + 0x7fffu + ((vb.u >> 16) & 1u);
  return __builtin_amdgcn_perm(tb, ta, 0x07060302);  // bytes [tb3 tb2 ta3 ta2]
}

// HW packed fp32->bf16 (RNE), 1 VALU op. No builtin on gfx950 -> inline asm (T12/m240).
__device__ inline unsigned cvtpk_bf16(float a, float b) {
  unsigned r;
  asm("v_cvt_pk_bf16_f32 %0, %1, %2" : "=v"(r) : "v"(a), "v"(b));
  return r;
}

// async global->LDS, 16 bytes per lane. HW writes lane L at (wave-uniform base)+L*16;
// we pass the per-lane pointer consistent with that (base = lane 0's pointer).
__device__ inline void async16(const void* g, void* l) {
  __builtin_amdgcn_global_load_lds(
      (const __attribute__((address_space(1))) unsigned int*)g,
      (__attribute__((address_space(3))) unsigned int*)l, 16, 0, 0);
}

// ---------- cast kernels: fp32 -> bf16 row-major (8 elems / thread) ----------
__device__ inline void cast8(const float* __restrict__ s, unsigned short* __restrict__ d) {
  float4 v0 = *(const float4*)s, v1 = *(const float4*)(s + 4);
  u32x4 o;
  o.x = packbf2(v0.x, v0.y); o.y = packbf2(v0.z, v0.w);
  o.z = packbf2(v1.x, v1.y); o.w = packbf2(v1.z, v1.w);
  *(u32x4*)d = o;
}

// x [8192][768] fp32 -> xs bf16 row-major. 6291456/8/256 = 3072 blocks.
__global__ __launch_bounds__(256) void cast_x(const float* __restrict__ x,
                                              unsigned short* __restrict__ xs) {
  size_t idx = (size_t)blockIdx.x * 256 + threadIdx.x;
  cast8(x + idx * 8, xs + idx * 8);
}

// qkv_w [2304][768] (221184 chunks) + proj_w [768][768] (73728 chunks) -> 1152 blocks.
// Boundary 221184 = 864*256 -> block-uniform branch.
__global__ __launch_bounds__(256) void cast_w(const float* __restrict__ wq,
                                              const float* __restrict__ wp,
                                              unsigned short* __restrict__ wqs,
                                              unsigned short* __restrict__ wps) {
  int idx = blockIdx.x * 256 + threadIdx.x;
  if (idx < 221184) cast8(wq + (size_t)idx * 8, wqs + (size_t)idx * 8);
  else {
    size_t j = (size_t)(idx - 221184) * 8;
    cast8(wp + j, wps + j);
  }
}

// ---------- GEMM, m97-structure: LDS-staged 128xTN tile, XOR-swizzled frag reads ----
// C[m][n] = sum_k A[m][k]*B[n][k], A row-major [M][768] bf16, B row-major [N][768] bf16.
// Block 256 threads = 4 waves (2x2). K-loop: 12 steps of BK=64 via global_load_lds
// width=16 (linear LDS dest, inverse-swizzled global source), ds_read_b128 frags with
// byte^((row&7)<<4) XOR-swizzle, 2x MFMA-K per step.
// MODE 0 (qkv): TN=128, grid (64,18).
//   r2 post-mortem: direct q/k/v stores caused 4.2x WRITE amplification (158 MB,
//   partial-sector RMW). Fix: LDS-TRANSPOSE EPILOGUE -- after the K-loop the 32KB
//   staging LDS is dead; write acc into a 128x128 bf16 tile (XOR-swizzled), barrier,
//   read back 16B/lane in address order -> every store instruction covers a fully
//   contiguous 4KB span (zero partial lines).
//   q/k thirds: swapped MFMA (lane holds 4 consecutive feats) -> LDS [tok][feat],
//   readout = 128B token rows. v third: normal MFMA (lane holds 4 consecutive toks)
//   -> LDS [feat][tok], readout = 256B token runs of v^T [B,H,D,N].
// MODE 1 (proj): TN=64, grid (64,12)=768 blocks. Direct fp32 stores (full 64B lines).
template<int MODE>
__global__ __launch_bounds__(256, 3) void gemm_lds(
    const unsigned short* __restrict__ A, const unsigned short* __restrict__ B,
    const float* __restrict__ bias,
    unsigned short* __restrict__ oq, unsigned short* __restrict__ ok,
    unsigned short* __restrict__ ov, float* __restrict__ of)
{
  constexpr int NI = (MODE == 0) ? 4 : 2;     // B fragments per wave
  constexpr int TN = NI * 32;                 // block N-tile
  __shared__ __align__(16) unsigned short lds[128 * 64 + TN * 64];  // 32 KB (MODE0)
  unsigned short* As = lds;
  unsigned short* Bs = lds + 128 * 64;

  const int t = threadIdx.x, w = t >> 6, lane = t & 63;
  const int quad = lane >> 4, l16 = lane & 15;
  const int bm = blockIdx.x, bn = blockIdx.y;
  const int wr = w >> 1, wc = w & 1;

  // q/k thirds get transposed output via operand swap (uniform per block).
  const bool swapped = (MODE == 0) && (bn < 12);

  // staging geometry: each instruction moves 8 rows x 128B (1KB / wave).
  const int r_off = lane >> 3;                 // row within 8-row chunk
  const int kb_lin = (lane & 7) << 4;          // byte offset within 128B row

  const unsigned short* Ag = A + (size_t)(bm * 128) * 768;
  const unsigned short* Bg = B + (size_t)(bn * TN) * 768;

  // Hoisted per-lane staging pointers. Source k-offset is the XOR-swizzle inverse
  // (involution, within-row), so linear LDS slot (r, kb) holds A[r][k0+(kb^((r&7)<<4))]
  // -> swizzled read returns A[r][k0+kb] exactly.
  const unsigned short* ApA[4]; unsigned short* LpA[4];
#pragma unroll
  for (int i = 0; i < 4; i++) {
    int r = w * 32 + i * 8 + r_off;
    int ks = (kb_lin ^ ((r & 7) << 4)) >> 1;
    ApA[i] = Ag + (size_t)r * 768 + ks;
    LpA[i] = As + (w * 32 + i * 8) * 64 + lane * 8;
  }
  const unsigned short* ApB[NI]; unsigned short* LpB[NI];
#pragma unroll
  for (int i = 0; i < NI; i++) {
    int r = w * (TN / 4) + i * 8 + r_off;
    int ks = (kb_lin ^ ((r & 7) << 4)) >> 1;
    ApB[i] = Bg + (size_t)r * 768 + ks;
    LpB[i] = Bs + (w * (TN / 4) + i * 8) * 64 + lane * 8;
  }

  f32x4 acc[4][NI] = {};
  const int swz = (l16 & 7) << 3;              // short-offset XOR for frag reads

  for (int kt = 0; kt < 12; kt++) {
    __syncthreads();                           // previous compute done reading LDS
    const int k0 = kt * 64;
#pragma unroll
    for (int i = 0; i < 4; i++)  async16(ApA[i] + k0, LpA[i]);
#pragma unroll
    for (int i = 0; i < NI; i++) async16(ApB[i] + k0, LpB[i]);
    __syncthreads();                           // compiler drains vmcnt before barrier

#pragma unroll
    for (int kc = 0; kc < 2; kc++) {
      const int ko = (kc * 32 + quad * 8) ^ swz;
      bf16x8 a[4], b[NI];
#pragma unroll
      for (int mi = 0; mi < 4; mi++)
        a[mi] = *(const bf16x8*)&As[(wr * 64 + mi * 16 + l16) * 64 + ko];
#pragma unroll
      for (int ni = 0; ni < NI; ni++)
        b[ni] = *(const bf16x8*)&Bs[(wc * (TN / 2) + ni * 16 + l16) * 64 + ko];
      if (swapped) {
#pragma unroll
        for (int mi = 0; mi < 4; mi++)
#pragma unroll
          for (int ni = 0; ni < NI; ni++)
            acc[mi][ni] = __builtin_amdgcn_mfma_f32_16x16x32_bf16(b[ni], a[mi],
                                                                  acc[mi][ni], 0, 0, 0);
      } else {
#pragma unroll
        for (int mi = 0; mi < 4; mi++)
#pragma unroll
          for (int ni = 0; ni < NI; ni++)
            acc[mi][ni] = __builtin_amdgcn_mfma_f32_16x16x32_bf16(a[mi], b[ni],
                                                                  acc[mi][ni], 0, 0, 0);
      }
    }
  }

  // ---- epilogue ----
  if (MODE == 0) {
    __syncthreads();                          // all waves done reading staging LDS
    char* Cb = (char*)lds;                    // 128x128 bf16 tile, 256 B rows, 32 KB
    const int three = (bn * 128) / 768;       // block-uniform (0=q, 1=k, 2=v)
    const int tok0 = bm * 128;
    const int b_ = tok0 >> 11, nt0 = tok0 & 2047;   // 2048 % 128 == 0 -> uniform
    if (three < 2) {
      // swapped acc: col(l16)=token, row(quad*4+r)=feature (4 consecutive).
      const float sc = (three == 0) ? QSCALE : 1.f;
#pragma unroll
      for (int ni = 0; ni < NI; ni++) {
        int nb = bn * 128 + wc * 64 + ni * 16 + (quad << 2);
        float4 b4 = *(const float4*)&bias[nb];
        int fB = wc * 128 + ni * 32 + quad * 8;        // feature byte offset in row
#pragma unroll
        for (int mi = 0; mi < 4; mi++) {
          int tl = wr * 64 + mi * 16 + l16;            // token-local (tl&15 == l16)
          u32x2 pv;
          pv.x = cvtpk_bf16((acc[mi][ni][0] + b4.x) * sc, (acc[mi][ni][1] + b4.y) * sc);
          pv.y = cvtpk_bf16((acc[mi][ni][2] + b4.z) * sc, (acc[mi][ni][3] + b4.w) * sc);
          *(u32x2*)(Cb + tl * 256 + (fB ^ ((tl & 15) << 4))) = pv;
        }
      }
      __syncthreads();
      unsigned short* o = (three == 0) ? oq : ok;
      const int h0 = (bn * 128 - three * 768) >> 6;
#pragma unroll
      for (int i = 0; i < 8; i++) {
        int c = i * 256 + t;
        int row = c >> 3, off = c & 7;                 // 8 x 16B chunks per 128B row
        int hh = row >> 7, tl = row & 127;
        u32x4 v = *(const u32x4*)(Cb + tl * 256 + ((hh * 128 + off * 16) ^ ((tl & 15) << 4)));
        *(u32x4*)(o + (((size_t)b_ * 12 + h0 + hh) * 2048 + nt0 + tl) * 64 + off * 8) = v;
      }
    } else {
      // v: normal acc: col(l16)=feature, row(quad*4+r)=token (4 consecutive).
#pragma unroll
      for (int ni = 0; ni < NI; ni++) {
        int fl = wc * 64 + ni * 16 + l16;              // feature-local (fl&15 == l16)
        float bs = bias[bn * 128 + fl];
#pragma unroll
        for (int mi = 0; mi < 4; mi++) {
          int tkB = (wr * 64 + mi * 16 + (quad << 2)) * 2;   // token byte offset
          u32x2 pv;
          pv.x = cvtpk_bf16(acc[mi][ni][0] + bs, acc[mi][ni][1] + bs);
          pv.y = cvtpk_bf16(acc[mi][ni][2] + bs, acc[mi][ni][3] + bs);
          *(u32x2*)(Cb + fl * 256 + (tkB ^ ((fl & 15) << 4))) = pv;
        }
      }
      __syncthreads();
#pragma unroll
      for (int i = 0; i < 8; i++) {
        int c = i * 256 + t;
        int fl = c >> 4, off = c & 15;                 // 16 x 16B chunks per 256B row
        u32x4 v = *(const u32x4*)(Cb + fl * 256 + ((off * 16) ^ ((fl & 15) << 4)));
        int rem = bn * 128 + fl - 1536;
        int h = rem >> 6, d = rem & 63;
        *(u32x4*)(ov + (((size_t)b_ * 12 + h) * 64 + d) * 2048 + nt0 + off * 8) = v;
      }
    }
  } else {
    const int m_base = bm * 128 + wr * 64;
#pragma unroll
    for (int ni = 0; ni < NI; ni++) {
      int n_g = bn * TN + wc * (TN / 2) + ni * 16 + l16;
      float bs = bias[n_g];
#pragma unroll
      for (int mi = 0; mi < 4; mi++)
#pragma unroll
        for (int r = 0; r < 4; r++) {
          int m_g = m_base + mi * 16 + (quad << 2) + r;
          of[(size_t)m_g * 768 + n_g] = acc[mi][ni][r] + bs;
        }
    }
  }
}

// ---------- flash attention: transposed-score + register-P; output row-major ----------
// Grid (48 bh, 16 qt): same-bh blocks 48 apart == 0 mod 8 -> same XCD (K/V L2 locality).
// r1->r2: v_cvt_pk_bf16_f32 packing, vector l-accumulator, hoisted zero C-in, setprio.
__global__ __launch_bounds__(256, 3) void flash_attn(
    const unsigned short* __restrict__ Qb, const unsigned short* __restrict__ Kb,
    const unsigned short* __restrict__ Vtb, unsigned short* __restrict__ ao)
{
  __shared__ unsigned short Ks[2][4096];   // slot(c,kvslot) = K[g(kvslot)][c*8..+8]
  __shared__ unsigned short Vs[2][4096];   // slot(c,d)      = V^T[d][c*8..+8]
  const int t = threadIdx.x, w = t >> 6, lane = t & 63;
  const int quad = lane >> 4, l16 = lane & 15;
  const int bh = blockIdx.x, qt = blockIdx.y;
  const unsigned short* Qg = Qb + (size_t)bh * 2048 * 64;
  const unsigned short* Kg = Kb + (size_t)bh * 2048 * 64;
  const unsigned short* Vg = Vtb + (size_t)bh * 2048 * 64;   // [64][2048]

  bf16x8 bq[2][2];
#pragma unroll
  for (int u = 0; u < 2; u++) {
    int qrow = qt * 128 + w * 32 + u * 16 + l16;
#pragma unroll
    for (int h = 0; h < 2; h++)
      bq[u][h] = *(const bf16x8*)(Qg + (size_t)qrow * 64 + h * 32 + quad * 8);
  }

  const int s0 = t, s1 = 256 + t;
  auto gperm = [](int s) { return (s & 0x23) | ((s & 0x0c) << 1) | ((s & 0x10) >> 2); };
  const size_t koff0 = (size_t)gperm(s0 & 63) * 64 + (s0 >> 6) * 8;
  const size_t koff1 = (size_t)gperm(s1 & 63) * 64 + (s1 >> 6) * 8;
  const size_t voff0 = (size_t)(s0 & 63) * 2048 + (s0 >> 6) * 8;
  const size_t voff1 = (size_t)(s1 & 63) * 2048 + (s1 >> 6) * 8;

  const f32x4 z4 = {0.f, 0.f, 0.f, 0.f};    // persistent MFMA C-in zero
  f32x4 lacc[2] = {z4, z4};                 // vector l accumulator
  f32x4 o_acc[2][4];
#pragma unroll
  for (int u = 0; u < 2; u++)
#pragma unroll
    for (int dt = 0; dt < 4; dt++) o_acc[u][dt] = z4;

  async16(Kg + koff0, &Ks[0][s0 * 8]);
  async16(Kg + koff1, &Ks[0][s1 * 8]);
  async16(Vg + voff0, &Vs[0][s0 * 8]);
  async16(Vg + voff1, &Vs[0][s1 * 8]);

  for (int kt = 0; kt < 32; kt++) {
    const int p = kt & 1;
    __syncthreads();
    if (kt < 31) {
      const unsigned short* Kn = Kg + (size_t)(kt + 1) * 4096;
      const unsigned short* Vn = Vg + (size_t)(kt + 1) * 64;
      async16(Kn + koff0, &Ks[p ^ 1][s0 * 8]);
      async16(Kn + koff1, &Ks[p ^ 1][s1 * 8]);
      async16(Vn + voff0, &Vs[p ^ 1][s0 * 8]);
      async16(Vn + voff1, &Vs[p ^ 1][s1 * 8]);
    }
    const unsigned short* Kp = &Ks[p][0];
    const unsigned short* Vp = &Vs[p][0];

    f32x4 sv[2][4];
    __builtin_amdgcn_s_setprio(1);
#pragma unroll
    for (int nt = 0; nt < 4; nt++) {
      bf16x8 k0 = *(const bf16x8*)&Kp[((quad) * 64 + nt * 16 + l16) * 8];
      bf16x8 k1 = *(const bf16x8*)&Kp[((4 + quad) * 64 + nt * 16 + l16) * 8];
#pragma unroll
      for (int u = 0; u < 2; u++) {
        f32x4 s_ = __builtin_amdgcn_mfma_f32_16x16x32_bf16(k0, bq[u][0], z4, 0, 0, 0);
        s_ = __builtin_amdgcn_mfma_f32_16x16x32_bf16(k1, bq[u][1], s_, 0, 0, 0);
        sv[u][nt] = s_;
      }
    }
    __builtin_amdgcn_s_setprio(0);

    union { unsigned u32[8]; bf16x8 v[2]; } pk[2];
#pragma unroll
    for (int u = 0; u < 2; u++) {
#pragma unroll
      for (int nt = 0; nt < 4; nt++) {
        float p0 = __builtin_amdgcn_exp2f(sv[u][nt][0]);
        float p1 = __builtin_amdgcn_exp2f(sv[u][nt][1]);
        float p2 = __builtin_amdgcn_exp2f(sv[u][nt][2]);
        float p3 = __builtin_amdgcn_exp2f(sv[u][nt][3]);
        lacc[u] += (f32x4){p0, p1, p2, p3};
        pk[u].u32[nt * 2]     = cvtpk_bf16(p0, p1);
        pk[u].u32[nt * 2 + 1] = cvtpk_bf16(p2, p3);
      }
    }

    __builtin_amdgcn_s_setprio(1);
#pragma unroll
    for (int cc = 0; cc < 2; cc++) {
#pragma unroll
      for (int dt = 0; dt < 4; dt++) {
        bf16x8 a = *(const bf16x8*)&Vp[((cc * 4 + quad) * 64 + dt * 16 + l16) * 8];
#pragma unroll
        for (int u = 0; u < 2; u++)
          o_acc[u][dt] = __builtin_amdgcn_mfma_f32_16x16x32_bf16(a, pk[u].v[cc], o_acc[u][dt], 0, 0, 0);
      }
    }
    __builtin_amdgcn_s_setprio(0);
  }

  float linv[2];
#pragma unroll
  for (int u = 0; u < 2; u++) {
    float l = (lacc[u][0] + lacc[u][1]) + (lacc[u][2] + lacc[u][3]);
    l += __shfl_xor(l, 16, 64);
    l += __shfl_xor(l, 32, 64);
    linv[u] = 1.f / l;
  }

  // epilogue: row = b_*2048 + qt*128 + w*32 + u*16 + l16 ; col = h*64 + dt*16 + quad*4
  const int b_ = bh / 12, h = bh - b_ * 12;
#pragma unroll
  for (int u = 0; u < 2; u++) {
    int row = b_ * 2048 + qt * 128 + w * 32 + u * 16 + l16;
    unsigned short* base = ao + (size_t)row * 768 + h * 64 + (quad << 2);
#pragma unroll
    for (int dt = 0; dt < 4; dt++) {
      u32x2 pv;
      pv.x = cvtpk_bf16(o_acc[u][dt][0] * linv[u], o_acc[u][dt][1] * linv[u]);
      pv.y = cvtpk_bf16(o_acc[u][dt][2] * linv[u], o_acc[u][dt][3] * linv[u]);
      *(u32x2*)(base + dt * 16) = pv;
    }
  }
}

// ---------- launch ----------
extern "C" void kernel_launch(void* const* d_in, const int* in_sizes, int n_in,
                              void* d_out, int out_size, void* d_ws, size_t ws_size,
                              hipStream_t stream) {
  const float* x      = (const float*)d_in[0];
  const float* qkv_w  = (const float*)d_in[1];
  const float* qkv_b  = (const float*)d_in[2];
  const float* proj_w = (const float*)d_in[3];
  const float* proj_b = (const float*)d_in[4];
  float* out = (float*)d_out;

  unsigned short* ws  = (unsigned short*)d_ws;
  unsigned short* wqs = ws;                  // 1769472  qkv_w  bf16 [2304][768]
  unsigned short* wps = wqs + 1769472;       // 589824   proj_w bf16 [768][768]
  unsigned short* xs  = wps + 589824;        // 6291456  x      bf16 [8192][768]
  unsigned short* qb  = xs + 6291456;        // 6291456  q bf16 [B,H,N,D] (pre-scaled)
  unsigned short* kb  = qb + 6291456;        // 6291456  k bf16 [B,H,N,D]
  unsigned short* vtb = kb + 6291456;        // 6291456  v bf16 [B,H,D,N] (transposed)
  unsigned short* ao  = vtb + 6291456;       // 6291456  attn-out bf16 [8192][768]

  cast_w<<<1152, 256, 0, stream>>>(qkv_w, proj_w, wqs, wps);
  cast_x<<<3072, 256, 0, stream>>>(x, xs);
  gemm_lds<0><<<dim3(64, 18), 256, 0, stream>>>(xs, wqs, qkv_b, qb, kb, vtb, nullptr);
  flash_attn<<<dim3(48, 16), 256, 0, stream>>>(qb, kb, vtb, ao);
  gemm_lds<1><<<dim3(64, 12), 256, 0, stream>>>(ao, wps, proj_b, nullptr, nullptr, nullptr, out);
}

// Round 6
// 196.337 us; speedup vs baseline: 1.3429x; 1.3429x over previous
//
#include <hip/hip_runtime.h>

// ---------- common types / helpers ----------
typedef __attribute__((ext_vector_type(8))) short bf16x8;   // 8 bf16 = 4 VGPRs
typedef __attribute__((ext_vector_type(4))) float f32x4;
typedef __attribute__((ext_vector_type(4))) unsigned int u32x4;
typedef __attribute__((ext_vector_type(2))) unsigned int u32x2;

// q pre-scale: softmax scale (1/sqrt(64)) * log2(e), so P = exp2(S) directly.
#define QSCALE 0.1803368801111243f

__device__ inline unsigned short f2bf(float f) {
  union { float f; unsigned u; } v; v.f = f;
  unsigned r = v.u + 0x7fffu + ((v.u >> 16) & 1u);   // RNE
  return (unsigned short)(r >> 16);
}

// pack two fp32 -> two bf16 (RNE) in one dword: low16 = bf(a), high16 = bf(b)
__device__ inline unsigned packbf2(float a, float b) {
  union { float f; unsigned u; } va, vb; va.f = a; vb.f = b;
  unsigned ta = va.u + 0x7fffu + ((va.u >> 16) & 1u);
  unsigned tb = vb.u + 0x7fffu + ((vb.u >> 16) & 1u);
  return __builtin_amdgcn_perm(tb, ta, 0x07060302);  // bytes [tb3 tb2 ta3 ta2]
}

// HW packed fp32->bf16 (RNE), 1 VALU op. No builtin on gfx950 -> inline asm (T12/m240).
__device__ inline unsigned cvtpk_bf16(float a, float b) {
  unsigned r;
  asm("v_cvt_pk_bf16_f32 %0, %1, %2" : "=v"(r) : "v"(a), "v"(b));
  return r;
}

// async global->LDS, 16 bytes per lane. HW writes lane L at (wave-uniform base)+L*16;
// we pass the per-lane pointer consistent with that (base = lane 0's pointer).
__device__ inline void async16(const void* g, void* l) {
  __builtin_amdgcn_global_load_lds(
      (const __attribute__((address_space(1))) unsigned int*)g,
      (__attribute__((address_space(3))) unsigned int*)l, 16, 0, 0);
}

// ---------- cast kernels: fp32 -> bf16 row-major (8 elems / thread) ----------
__device__ inline void cast8(const float* __restrict__ s, unsigned short* __restrict__ d) {
  float4 v0 = *(const float4*)s, v1 = *(const float4*)(s + 4);
  u32x4 o;
  o.x = packbf2(v0.x, v0.y); o.y = packbf2(v0.z, v0.w);
  o.z = packbf2(v1.x, v1.y); o.w = packbf2(v1.z, v1.w);
  *(u32x4*)d = o;
}

// x [8192][768] fp32 -> xs bf16 row-major. 6291456/8/256 = 3072 blocks.
__global__ __launch_bounds__(256) void cast_x(const float* __restrict__ x,
                                              unsigned short* __restrict__ xs) {
  size_t idx = (size_t)blockIdx.x * 256 + threadIdx.x;
  cast8(x + idx * 8, xs + idx * 8);
}

// qkv_w [2304][768] (221184 chunks) + proj_w [768][768] (73728 chunks) -> 1152 blocks.
// Boundary 221184 = 864*256 -> block-uniform branch.
__global__ __launch_bounds__(256) void cast_w(const float* __restrict__ wq,
                                              const float* __restrict__ wp,
                                              unsigned short* __restrict__ wqs,
                                              unsigned short* __restrict__ wps) {
  int idx = blockIdx.x * 256 + threadIdx.x;
  if (idx < 221184) cast8(wq + (size_t)idx * 8, wqs + (size_t)idx * 8);
  else {
    size_t j = (size_t)(idx - 221184) * 8;
    cast8(wp + j, wps + j);
  }
}

// ---------- GEMM: LDS-staged 128xTN tile, double-buffered single-barrier K-loop ----
// C[m][n] = sum_k A[m][k]*B[n][k], A row-major [M][768] bf16, B row-major [N][768] bf16.
// Block 256 threads = 4 waves (2x2).
// K-loop (T3-minimum, guide §5.5): per step, issue stage(t+1) into the OTHER LDS
// buffer FIRST, then ds_read+MFMA on buf[t&1], then ONE __syncthreads() (its
// vmcnt(0)-drain now lands the prefetch under this step's compute instead of
// serializing before it). Race-free: passing barrier(t) => all waves finished
// compute(t) and stage(t+1) landed, so step t+1 may read buf[t+1] and overwrite
// buf[t]. Removes the per-step full-latency drain (r5 counters: MfmaUtil 10%,
// VALUBusy 7%, occupancy 25% -- pure latency-bound).
// Epilogue: ROUND-1 style (empirically best: r1 gemm0 <80us vs r2 swap-scatter
// 100us vs r5 LDS-transpose 107us). No operand swap.
// MODE 0 (qkv): TN=128, grid (64,18). q/k scalar stores ni-innermost; v u32x2.
// MODE 1 (proj): TN=64, grid (64,12). Direct fp32 stores (full 64B lines).
template<int MODE>
__global__ __launch_bounds__(256, MODE == 0 ? 2 : 3) void gemm_lds(
    const unsigned short* __restrict__ A, const unsigned short* __restrict__ B,
    const float* __restrict__ bias,
    unsigned short* __restrict__ oq, unsigned short* __restrict__ ok,
    unsigned short* __restrict__ ov, float* __restrict__ of)
{
  constexpr int NI = (MODE == 0) ? 4 : 2;     // B fragments per wave
  constexpr int TN = NI * 32;                 // block N-tile
  constexpr int LSTR = 128 * 64 + TN * 64;    // shorts per buffer
  __shared__ __align__(16) unsigned short lds[2][LSTR];   // 64 KB (MODE0) / 48 KB
  unsigned short* As = &lds[0][0];
  unsigned short* Bs = &lds[0][128 * 64];

  const int t = threadIdx.x, w = t >> 6, lane = t & 63;
  const int quad = lane >> 4, l16 = lane & 15;
  const int bm = blockIdx.x, bn = blockIdx.y;
  const int wr = w >> 1, wc = w & 1;

  // staging geometry: each instruction moves 8 rows x 128B (1KB / wave).
  const int r_off = lane >> 3;                 // row within 8-row chunk
  const int kb_lin = (lane & 7) << 4;          // byte offset within 128B row

  const unsigned short* Ag = A + (size_t)(bm * 128) * 768;
  const unsigned short* Bg = B + (size_t)(bn * TN) * 768;

  // Hoisted per-lane staging pointers. Source k-offset is the XOR-swizzle inverse
  // (involution, within-row), so linear LDS slot (r, kb) holds A[r][k0+(kb^((r&7)<<4))]
  // -> swizzled read returns A[r][k0+kb] exactly.
  const unsigned short* ApA[4]; unsigned short* LpA[4];
#pragma unroll
  for (int i = 0; i < 4; i++) {
    int r = w * 32 + i * 8 + r_off;
    int ks = (kb_lin ^ ((r & 7) << 4)) >> 1;
    ApA[i] = Ag + (size_t)r * 768 + ks;
    LpA[i] = As + (w * 32 + i * 8) * 64 + lane * 8;
  }
  const unsigned short* ApB[NI]; unsigned short* LpB[NI];
#pragma unroll
  for (int i = 0; i < NI; i++) {
    int r = w * (TN / 4) + i * 8 + r_off;
    int ks = (kb_lin ^ ((r & 7) << 4)) >> 1;
    ApB[i] = Bg + (size_t)r * 768 + ks;
    LpB[i] = Bs + (w * (TN / 4) + i * 8) * 64 + lane * 8;
  }

  f32x4 acc[4][NI] = {};
  const int swz = (l16 & 7) << 3;              // short-offset XOR for frag reads

  // prologue: stage tile 0 into buf0, drain, barrier
#pragma unroll
  for (int i = 0; i < 4; i++)  async16(ApA[i], LpA[i]);
#pragma unroll
  for (int i = 0; i < NI; i++) async16(ApB[i], LpB[i]);
  __syncthreads();

  for (int kt = 0; kt < 12; kt++) {
    const int cur = kt & 1;
    if (kt < 11) {                             // issue next tile's loads FIRST
      const int k1 = (kt + 1) * 64;
      const int nb = (cur ^ 1) * LSTR;
#pragma unroll
      for (int i = 0; i < 4; i++)  async16(ApA[i] + k1, LpA[i] + nb);
#pragma unroll
      for (int i = 0; i < NI; i++) async16(ApB[i] + k1, LpB[i] + nb);
    }
    const unsigned short* Ac = As + cur * LSTR;
    const unsigned short* Bc = Bs + cur * LSTR;
#pragma unroll
    for (int kc = 0; kc < 2; kc++) {
      const int ko = (kc * 32 + quad * 8) ^ swz;
      bf16x8 a[4], b[NI];
#pragma unroll
      for (int mi = 0; mi < 4; mi++)
        a[mi] = *(const bf16x8*)&Ac[(wr * 64 + mi * 16 + l16) * 64 + ko];
#pragma unroll
      for (int ni = 0; ni < NI; ni++)
        b[ni] = *(const bf16x8*)&Bc[(wc * (TN / 2) + ni * 16 + l16) * 64 + ko];
#pragma unroll
      for (int mi = 0; mi < 4; mi++)
#pragma unroll
        for (int ni = 0; ni < NI; ni++)
          acc[mi][ni] = __builtin_amdgcn_mfma_f32_16x16x32_bf16(a[mi], b[ni],
                                                                acc[mi][ni], 0, 0, 0);
    }
    __syncthreads();   // drains vmcnt(0): stage(kt+1) landed; all waves done with cur
  }

  // ---- epilogue ----  C/D layout: col(n) = l16, row(m) = quad*4 + r
  const int m_base = bm * 128 + wr * 64;
  if (MODE == 0) {
    const int three = (bn * 128) / 768;        // block-uniform (768 % 128 == 0)
    int hh[NI], dd[NI]; float bb[NI];
#pragma unroll
    for (int ni = 0; ni < NI; ni++) {
      int n_g = bn * 128 + wc * 64 + ni * 16 + l16;
      bb[ni] = bias[n_g];
      int rem = n_g - three * 768;
      hh[ni] = rem >> 6; dd[ni] = rem & 63;
    }
    if (three == 2) {
      // v -> [B,H,D,N]: lane's 4 r-values are 4 consecutive tokens -> one 8B store.
#pragma unroll
      for (int ni = 0; ni < NI; ni++)
#pragma unroll
        for (int mi = 0; mi < 4; mi++) {
          int m0 = m_base + mi * 16 + (quad << 2);
          int b_ = m0 >> 11, ntok = m0 & 2047;
          u32x2 pv;
          pv.x = cvtpk_bf16(acc[mi][ni][0] + bb[ni], acc[mi][ni][1] + bb[ni]);
          pv.y = cvtpk_bf16(acc[mi][ni][2] + bb[ni], acc[mi][ni][3] + bb[ni]);
          *(u32x2*)(ov + (((size_t)b_ * 12 + hh[ni]) * 64 + dd[ni]) * 2048 + ntok) = pv;
        }
    } else {
      unsigned short* o = (three == 0) ? oq : ok;
      const float sc = (three == 0) ? QSCALE : 1.f;
#pragma unroll
      for (int mi = 0; mi < 4; mi++)
#pragma unroll
        for (int r = 0; r < 4; r++) {
          int m_g = m_base + mi * 16 + (quad << 2) + r;
          int b_ = m_g >> 11, ntok = m_g & 2047;
          size_t rowb = ((size_t)b_ * 12) * 2048;
#pragma unroll
          for (int ni = 0; ni < NI; ni++) {   // ni innermost: adjacent 32B halves merge
            float v = (acc[mi][ni][r] + bb[ni]) * sc;
            o[((rowb + (size_t)hh[ni] * 2048 + ntok) << 6) + dd[ni]] = f2bf(v);
          }
        }
    }
  } else {
#pragma unroll
    for (int ni = 0; ni < NI; ni++) {
      int n_g = bn * TN + wc * (TN / 2) + ni * 16 + l16;
      float bs = bias[n_g];
#pragma unroll
      for (int mi = 0; mi < 4; mi++)
#pragma unroll
        for (int r = 0; r < 4; r++) {
          int m_g = m_base + mi * 16 + (quad << 2) + r;
          of[(size_t)m_g * 768 + n_g] = acc[mi][ni][r] + bs;
        }
    }
  }
}

// ---------- flash attention: transposed-score + register-P; output row-major ----------
// Grid (48 bh, 16 qt): same-bh blocks 48 apart == 0 mod 8 -> same XCD (K/V L2 locality).
// r1->r2: v_cvt_pk_bf16_f32 packing, vector l-accumulator, hoisted zero C-in, setprio.
// Loop already has the single-barrier stage-then-compute form.
__global__ __launch_bounds__(256, 3) void flash_attn(
    const unsigned short* __restrict__ Qb, const unsigned short* __restrict__ Kb,
    const unsigned short* __restrict__ Vtb, unsigned short* __restrict__ ao)
{
  __shared__ unsigned short Ks[2][4096];   // slot(c,kvslot) = K[g(kvslot)][c*8..+8]
  __shared__ unsigned short Vs[2][4096];   // slot(c,d)      = V^T[d][c*8..+8]
  const int t = threadIdx.x, w = t >> 6, lane = t & 63;
  const int quad = lane >> 4, l16 = lane & 15;
  const int bh = blockIdx.x, qt = blockIdx.y;
  const unsigned short* Qg = Qb + (size_t)bh * 2048 * 64;
  const unsigned short* Kg = Kb + (size_t)bh * 2048 * 64;
  const unsigned short* Vg = Vtb + (size_t)bh * 2048 * 64;   // [64][2048]

  bf16x8 bq[2][2];
#pragma unroll
  for (int u = 0; u < 2; u++) {
    int qrow = qt * 128 + w * 32 + u * 16 + l16;
#pragma unroll
    for (int h = 0; h < 2; h++)
      bq[u][h] = *(const bf16x8*)(Qg + (size_t)qrow * 64 + h * 32 + quad * 8);
  }

  const int s0 = t, s1 = 256 + t;
  auto gperm = [](int s) { return (s & 0x23) | ((s & 0x0c) << 1) | ((s & 0x10) >> 2); };
  const size_t koff0 = (size_t)gperm(s0 & 63) * 64 + (s0 >> 6) * 8;
  const size_t koff1 = (size_t)gperm(s1 & 63) * 64 + (s1 >> 6) * 8;
  const size_t voff0 = (size_t)(s0 & 63) * 2048 + (s0 >> 6) * 8;
  const size_t voff1 = (size_t)(s1 & 63) * 2048 + (s1 >> 6) * 8;

  const f32x4 z4 = {0.f, 0.f, 0.f, 0.f};    // persistent MFMA C-in zero
  f32x4 lacc[2] = {z4, z4};                 // vector l accumulator
  f32x4 o_acc[2][4];
#pragma unroll
  for (int u = 0; u < 2; u++)
#pragma unroll
    for (int dt = 0; dt < 4; dt++) o_acc[u][dt] = z4;

  async16(Kg + koff0, &Ks[0][s0 * 8]);
  async16(Kg + koff1, &Ks[0][s1 * 8]);
  async16(Vg + voff0, &Vs[0][s0 * 8]);
  async16(Vg + voff1, &Vs[0][s1 * 8]);

  for (int kt = 0; kt < 32; kt++) {
    const int p = kt & 1;
    __syncthreads();
    if (kt < 31) {
      const unsigned short* Kn = Kg + (size_t)(kt + 1) * 4096;
      const unsigned short* Vn = Vg + (size_t)(kt + 1) * 64;
      async16(Kn + koff0, &Ks[p ^ 1][s0 * 8]);
      async16(Kn + koff1, &Ks[p ^ 1][s1 * 8]);
      async16(Vn + voff0, &Vs[p ^ 1][s0 * 8]);
      async16(Vn + voff1, &Vs[p ^ 1][s1 * 8]);
    }
    const unsigned short* Kp = &Ks[p][0];
    const unsigned short* Vp = &Vs[p][0];

    f32x4 sv[2][4];
    __builtin_amdgcn_s_setprio(1);
#pragma unroll
    for (int nt = 0; nt < 4; nt++) {
      bf16x8 k0 = *(const bf16x8*)&Kp[((quad) * 64 + nt * 16 + l16) * 8];
      bf16x8 k1 = *(const bf16x8*)&Kp[((4 + quad) * 64 + nt * 16 + l16) * 8];
#pragma unroll
      for (int u = 0; u < 2; u++) {
        f32x4 s_ = __builtin_amdgcn_mfma_f32_16x16x32_bf16(k0, bq[u][0], z4, 0, 0, 0);
        s_ = __builtin_amdgcn_mfma_f32_16x16x32_bf16(k1, bq[u][1], s_, 0, 0, 0);
        sv[u][nt] = s_;
      }
    }
    __builtin_amdgcn_s_setprio(0);

    union { unsigned u32[8]; bf16x8 v[2]; } pk[2];
#pragma unroll
    for (int u = 0; u < 2; u++) {
#pragma unroll
      for (int nt = 0; nt < 4; nt++) {
        float p0 = __builtin_amdgcn_exp2f(sv[u][nt][0]);
        float p1 = __builtin_amdgcn_exp2f(sv[u][nt][1]);
        float p2 = __builtin_amdgcn_exp2f(sv[u][nt][2]);
        float p3 = __builtin_amdgcn_exp2f(sv[u][nt][3]);
        lacc[u] += (f32x4){p0, p1, p2, p3};
        pk[u].u32[nt * 2]     = cvtpk_bf16(p0, p1);
        pk[u].u32[nt * 2 + 1] = cvtpk_bf16(p2, p3);
      }
    }

    __builtin_amdgcn_s_setprio(1);
#pragma unroll
    for (int cc = 0; cc < 2; cc++) {
#pragma unroll
      for (int dt = 0; dt < 4; dt++) {
        bf16x8 a = *(const bf16x8*)&Vp[((cc * 4 + quad) * 64 + dt * 16 + l16) * 8];
#pragma unroll
        for (int u = 0; u < 2; u++)
          o_acc[u][dt] = __builtin_amdgcn_mfma_f32_16x16x32_bf16(a, pk[u].v[cc], o_acc[u][dt], 0, 0, 0);
      }
    }
    __builtin_amdgcn_s_setprio(0);
  }

  float linv[2];
#pragma unroll
  for (int u = 0; u < 2; u++) {
    float l = (lacc[u][0] + lacc[u][1]) + (lacc[u][2] + lacc[u][3]);
    l += __shfl_xor(l, 16, 64);
    l += __shfl_xor(l, 32, 64);
    linv[u] = 1.f / l;
  }

  // epilogue: row = b_*2048 + qt*128 + w*32 + u*16 + l16 ; col = h*64 + dt*16 + quad*4
  const int b_ = bh / 12, h = bh - b_ * 12;
#pragma unroll
  for (int u = 0; u < 2; u++) {
    int row = b_ * 2048 + qt * 128 + w * 32 + u * 16 + l16;
    unsigned short* base = ao + (size_t)row * 768 + h * 64 + (quad << 2);
#pragma unroll
    for (int dt = 0; dt < 4; dt++) {
      u32x2 pv;
      pv.x = cvtpk_bf16(o_acc[u][dt][0] * linv[u], o_acc[u][dt][1] * linv[u]);
      pv.y = cvtpk_bf16(o_acc[u][dt][2] * linv[u], o_acc[u][dt][3] * linv[u]);
      *(u32x2*)(base + dt * 16) = pv;
    }
  }
}

// ---------- launch ----------
extern "C" void kernel_launch(void* const* d_in, const int* in_sizes, int n_in,
                              void* d_out, int out_size, void* d_ws, size_t ws_size,
                              hipStream_t stream) {
  const float* x      = (const float*)d_in[0];
  const float* qkv_w  = (const float*)d_in[1];
  const float* qkv_b  = (const float*)d_in[2];
  const float* proj_w = (const float*)d_in[3];
  const float* proj_b = (const float*)d_in[4];
  float* out = (float*)d_out;

  unsigned short* ws  = (unsigned short*)d_ws;
  unsigned short* wqs = ws;                  // 1769472  qkv_w  bf16 [2304][768]
  unsigned short* wps = wqs + 1769472;       // 589824   proj_w bf16 [768][768]
  unsigned short* xs  = wps + 589824;        // 6291456  x      bf16 [8192][768]
  unsigned short* qb  = xs + 6291456;        // 6291456  q bf16 [B,H,N,D] (pre-scaled)
  unsigned short* kb  = qb + 6291456;        // 6291456  k bf16 [B,H,N,D]
  unsigned short* vtb = kb + 6291456;        // 6291456  v bf16 [B,H,D,N] (transposed)
  unsigned short* ao  = vtb + 6291456;       // 6291456  attn-out bf16 [8192][768]

  cast_w<<<1152, 256, 0, stream>>>(qkv_w, proj_w, wqs, wps);
  cast_x<<<3072, 256, 0, stream>>>(x, xs);
  gemm_lds<0><<<dim3(64, 18), 256, 0, stream>>>(xs, wqs, qkv_b, qb, kb, vtb, nullptr);
  flash_attn<<<dim3(48, 16), 256, 0, stream>>>(qb, kb, vtb, ao);
  gemm_lds<1><<<dim3(64, 12), 256, 0, stream>>>(ao, wps, proj_b, nullptr, nullptr, nullptr, out);
}